// Round 2
// baseline (1006.896 us; speedup 1.0000x reference)
//
#include <hip/hip_runtime.h>
#include <math.h>

#define NTOK 1024
#define NSTEPS 11
#define THREEFRY_PARTITIONABLE 1   // modern jax default; set 0 for legacy stream

// ---------- exact-fp32 helpers (block fp-contraction) ----------
__device__ __forceinline__ float fadd_(float a, float b){ return __fadd_rn(a,b); }
__device__ __forceinline__ float fsub_(float a, float b){ return __fsub_rn(a,b); }
__device__ __forceinline__ float fmul_(float a, float b){ return __fmul_rn(a,b); }

// jnp: (x + pi) % (2pi) - pi  ; jnp.mod = fmod (exact) + floor-mod fixup
__device__ __forceinline__ float wrap_angle(float x){
  const float PI_F     = 3.14159265358979323846f;   // 0x40490FDB
  const float TWO_PI_F = 6.28318530717958647692f;   // 0x40C90FDB
  float t = fadd_(x, PI_F);
  float r = fmodf(t, TWO_PI_F);
  if (r < 0.0f) r = fadd_(r, TWO_PI_F);             // (-0<0)==false, matches jnp
  return fsub_(r, PI_F);
}

// ---------- threefry2x32 (exact jax schedule) ----------
__device__ __forceinline__ void tf2x32(unsigned k0, unsigned k1,
                                       unsigned c0, unsigned c1,
                                       unsigned &o0, unsigned &o1){
  unsigned ks2 = k0 ^ k1 ^ 0x1BD11BDAu;
  unsigned x0 = c0 + k0, x1 = c1 + k1;
#define TFR(r) { x0 += x1; x1 = (x1 << (r)) | (x1 >> (32 - (r))); x1 ^= x0; }
  TFR(13) TFR(15) TFR(26) TFR(6)   x0 += k1;  x1 += ks2 + 1u;
  TFR(17) TFR(29) TFR(16) TFR(24)  x0 += ks2; x1 += k0  + 2u;
  TFR(13) TFR(15) TFR(26) TFR(6)   x0 += k0;  x1 += k1  + 3u;
  TFR(17) TFR(29) TFR(16) TFR(24)  x0 += k1;  x1 += ks2 + 4u;
  TFR(13) TFR(15) TFR(26) TFR(6)   x0 += ks2; x1 += k0  + 5u;
#undef TFR
  o0 = x0; o1 = x1;
}

// jax uniform(minval=tiny,maxval=1): u = bitcast(0x3f800000|(bits>>9)) - 1;
// r = u*(1-tiny)+tiny = u+tiny (since (1-tiny) rounds to 1.0f); max(tiny,r)=r.
// gumbel = -log(-log(r)); logs via double (≈correctly-rounded f32)
__device__ __forceinline__ float gumbel_from_bits(unsigned bits){
  unsigned m = bits >> 9;
  float u = (m == 0u) ? 1.17549435e-38f
                      : fsub_(__uint_as_float(0x3F800000u | m), 1.0f);
  float l1 = (float)log((double)u);
  float l2 = (float)log((double)(-l1));
  return -l2;
}

extern "C" __global__ void __launch_bounds__(256)
sctoken_kernel(const int* __restrict__ valid,
               const float* __restrict__ pos,
               const float* __restrict__ heading,
               const float* __restrict__ tok,
               float* __restrict__ out)
{
  __shared__ float2 s_txy[NTOK];                 // 8 KB
  __shared__ float  s_th[NTOK];                  // 4 KB
  __shared__ float  s_cpx[4][12], s_cpy[4][12], s_ch[4][12];
  __shared__ int    s_cv[4][12];

  const int tid = threadIdx.x;
  for (int j = tid; j < NTOK; j += 256) {
    s_txy[j] = make_float2(tok[3*j], tok[3*j+1]);
    s_th[j]  = tok[3*j+2];
  }
  const int wave = tid >> 6;
  const int lane = tid & 63;
  const int a = blockIdx.x * 4 + wave;

  const int*   va = valid   + a * 96;
  const float* ha = heading + a * 96;
  const float* pa = pos     + a * 192;

  // ---------------- phase 1+2: clean_heading + extrapolate_stationary ----------------
  {
    float hprev = ha[0];
    int   vprev = va[0];
    int   t = 0; bool seen = (vprev != 0);
    float ptx = pa[0], pty = pa[1], hth = hprev;
    if (lane == 0) {
      s_cv[wave][0] = vprev; s_cpx[wave][0] = pa[0]; s_cpy[wave][0] = pa[1]; s_ch[wave][0] = hprev;
    }
    for (int s = 1; s < 96; ++s) {
      int vcur = va[s];
      float hn = ha[s];
      float diff = fabsf(wrap_angle(fsub_(hprev, hn)));
      float hnew = ((diff > 1.5f) && vprev && vcur) ? hprev : hn;
      if (!seen && vcur) { seen = true; t = s; ptx = pa[2*s]; pty = pa[2*s+1]; hth = hnew; }
      if (((s & 7) == 0) && (s <= 88) && (lane == 0)) {
        int i = s >> 3;
        s_cv[wave][i] = vcur; s_cpx[wave][i] = pa[2*s]; s_cpy[wave][i] = pa[2*s+1]; s_ch[wave][i] = hnew;
      }
      hprev = hnew; vprev = vcur;
    }
    int n_fill = t & 7;
    if ((t == 16) && (va[8] == 0)) n_fill = 8;
    if ((lane == 0) && (n_fill > 0)) {
      int c = t - n_fill;             // multiple of 8, <= 88; only scan-visible col in mask
      int i = c >> 3;
      s_cv[wave][i] = 1; s_cpx[wave][i] = ptx; s_cpy[wave][i] = pty; s_ch[wave][i] = hth;
    }
  }
  __syncthreads();

  // ---------------- phase 3: 11-step match/sample scan ----------------
  unsigned k0 = 0u, k1 = 42u;                    // jax.random.key(42)
  float gpx = s_cpx[wave][0], gpy = s_cpy[wave][0], ghd = s_ch[wave][0];
  float spx = gpx, spy = gpy, shd = ghd;
  const unsigned long long FULL = ~0ULL;

  #pragma unroll 1
  for (int st = 0; st < NSTEPS; ++st) {
    unsigned nk0, nk1, sk0, sk1;
#if THREEFRY_PARTITIONABLE
    tf2x32(k0, k1, 0u, 0u, nk0, nk1);            // foldlike split row 0 -> carried key
    tf2x32(k0, k1, 0u, 1u, sk0, sk1);            // row 1 -> subkey
#else
    { unsigned a0,b0,a1,b1;
      tf2x32(k0, k1, 0u, 2u, a0, b0);            // counts [0,1,2,3]: blocks (0,2),(1,3)
      tf2x32(k0, k1, 1u, 3u, a1, b1);
      nk0 = a0; nk1 = a1; sk0 = b0; sk1 = b1; }
#endif
    k0 = nk0; k1 = nk1;

    const int  vprev  = s_cv[wave][st];
    const int  vcur   = s_cv[wave][st+1];
    const bool valid_ = (vprev != 0) && (vcur != 0);
    const float pix = s_cpx[wave][st+1];
    const float piy = s_cpy[wave][st+1];
    const float hin = s_ch[wave][st+1];
    const int oi = a * NSTEPS + st;

    // ======== GT branch: argmin over 1024 tokens ========
    {
      float c = (float)cos((double)ghd);
      float s = (float)sin((double)ghd);
      unsigned long long best = FULL;
      #pragma unroll
      for (int i2 = 0; i2 < 16; ++i2) {
        int j = lane + (i2 << 6);
        float2 t2 = s_txy[j];
        float gx = fadd_(fsub_(fmul_(c, t2.x), fmul_(s, t2.y)), gpx);
        float gy = fadd_(fadd_(fmul_(s, t2.x), fmul_(c, t2.y)), gpy);
        float dx = fsub_(gx, pix), dy = fsub_(gy, piy);
        float d  = fadd_(fmul_(dx, dx), fmul_(dy, dy));
        unsigned long long pk = (((unsigned long long)__float_as_uint(d)) << 10) | (unsigned)j;
        best = pk < best ? pk : best;
      }
      for (int off = 32; off > 0; off >>= 1) {
        unsigned long long o = __shfl_xor(best, off, 64);
        best = o < best ? o : best;
      }
      int jgt = (int)(best & 1023ULL);
      float2 t2 = s_txy[jgt];
      float gx = fadd_(fsub_(fmul_(c, t2.x), fmul_(s, t2.y)), gpx);
      float gy = fadd_(fadd_(fmul_(s, t2.x), fmul_(c, t2.y)), gpy);
      float nh = wrap_angle(fadd_(ghd, s_th[jgt]));
      float upx = valid_ ? gx : pix;
      float upy = valid_ ? gy : piy;
      float uhd = valid_ ? nh : hin;
      gpx = upx; gpy = upy; ghd = uhd;
      if (lane == 0) {
        out[oi]                = valid_ ? 1.0f : 0.0f;   // _valid
        out[90112  + oi]       = (float)jgt;             // idx_gt
        out[180224 + 2*oi]     = valid_ ? upx : 0.0f;    // gt_pos
        out[180224 + 2*oi + 1] = valid_ ? upy : 0.0f;
        out[360448 + oi]       = valid_ ? uhd : 0.0f;    // gt_head
      }
    }

    // ======== sampled branch: sorted top-32 + gumbel-argmax ========
    {
      float c = (float)cos((double)shd);
      float s = (float)sin((double)shd);
      unsigned long long dp[16];
      #pragma unroll
      for (int i2 = 0; i2 < 16; ++i2) {
        int j = lane + (i2 << 6);
        float2 t2 = s_txy[j];
        float gx = fadd_(fsub_(fmul_(c, t2.x), fmul_(s, t2.y)), spx);
        float gy = fadd_(fadd_(fmul_(s, t2.x), fmul_(c, t2.y)), spy);
        float dx = fsub_(gx, pix), dy = fsub_(gy, piy);
        float d  = fadd_(fmul_(dx, dx), fmul_(dy, dy));
        dp[i2] = (((unsigned long long)__float_as_uint(d)) << 10) | (unsigned)j;
      }
      float myv = 0.0f; int myj = 0;   // lane k<32 keeps k-th (value, index)
      #pragma unroll 1
      for (int k = 0; k < 32; ++k) {
        unsigned long long b = dp[0];
        #pragma unroll
        for (int i2 = 1; i2 < 16; ++i2) b = dp[i2] < b ? dp[i2] : b;
        for (int off = 32; off > 0; off >>= 1) {
          unsigned long long o = __shfl_xor(b, off, 64);
          b = o < b ? o : b;
        }
        int jw = (int)(b & 1023ULL);
        if (lane == k) { myv = -__uint_as_float((unsigned)(b >> 10)); myj = jw; }
        bool own = ((jw & 63) == lane);
        int slot = jw >> 6;
        #pragma unroll
        for (int i2 = 0; i2 < 16; ++i2)
          if (own && (slot == i2)) dp[i2] = FULL;
      }
      float cand;
      if (lane < 32) {
        unsigned b1, b2;
#if THREEFRY_PARTITIONABLE
        tf2x32(sk0, sk1, 0u, (unsigned)(a * 32 + lane), b1, b2);
        unsigned bits = b1 ^ b2;
#else
        unsigned flat = (unsigned)(a * 32 + lane);
        unsigned w0, w1;
        unsigned bits;
        if (flat < 131072u) { tf2x32(sk0, sk1, flat, flat + 131072u, w0, w1); bits = w0; }
        else                { tf2x32(sk0, sk1, flat - 131072u, flat, w0, w1); bits = w1; }
#endif
        float g = gumbel_from_bits(bits);
        cand = fadd_(myv, g);           // logits/TEMP(=1) + gumbel
      } else {
        cand = -INFINITY;
      }
      // argmax with first-occurrence tie-break (smaller k wins)
      unsigned mu = __float_as_uint(cand);
      mu = (mu & 0x80000000u) ? ~mu : (mu | 0x80000000u);
      unsigned long long mk = (((unsigned long long)mu) << 6) | (unsigned)(63 - lane);
      for (int off = 32; off > 0; off >>= 1) {
        unsigned long long o = __shfl_xor(mk, off, 64);
        mk = o > mk ? o : mk;
      }
      int kl = 63 - (int)(mk & 63ULL);
      int js = __shfl(myj, kl, 64);
      float2 t2 = s_txy[js];
      float gx = fadd_(fsub_(fmul_(c, t2.x), fmul_(s, t2.y)), spx);
      float gy = fadd_(fadd_(fmul_(s, t2.x), fmul_(c, t2.y)), spy);
      float nh = wrap_angle(fadd_(shd, s_th[js]));
      float upx = valid_ ? gx : pix;
      float upy = valid_ ? gy : piy;
      float uhd = valid_ ? nh : hin;
      spx = upx; spy = upy; shd = uhd;
      if (lane == 0) {
        out[450560 + oi]       = (float)js;              // idx_s
        out[540672 + 2*oi]     = valid_ ? upx : 0.0f;    // s_pos
        out[540672 + 2*oi + 1] = valid_ ? upy : 0.0f;
        out[720896 + oi]       = valid_ ? uhd : 0.0f;    // s_head
      }
    }
  }
}

extern "C" void kernel_launch(void* const* d_in, const int* in_sizes, int n_in,
                              void* d_out, int out_size, void* d_ws, size_t ws_size,
                              hipStream_t stream) {
  const int*   valid   = (const int*)  d_in[0];
  const float* pos     = (const float*)d_in[1];
  const float* heading = (const float*)d_in[2];
  const float* tok     = (const float*)d_in[3];
  float* out           = (float*)d_out;
  (void)in_sizes; (void)n_in; (void)out_size; (void)d_ws; (void)ws_size;
  // 8192 agents, 1 wave (64 lanes) per agent, 4 agents per 256-thread block
  hipLaunchKernelGGL(sctoken_kernel, dim3(2048), dim3(256), 0, stream,
                     valid, pos, heading, tok, out);
}